// Round 1
// baseline (201.798 us; speedup 1.0000x reference)
//
#include <hip/hip_runtime.h>

typedef unsigned short u16;
typedef __fp16 halfx8 __attribute__((ext_vector_type(8)));
typedef float floatx4 __attribute__((ext_vector_type(4)));
typedef unsigned short u16x4 __attribute__((ext_vector_type(4)));

#define D_MODEL 768
#define NH 12
#define DH 64
#define SEQ 2048
#define BATCH 2
#define MTOK 4096            // BATCH*SEQ
#define DQKV 2304

__device__ __forceinline__ u16 f2h(float f) {
    __fp16 h = (__fp16)f;
    return __builtin_bit_cast(u16, h);
}

__device__ __forceinline__ void gload_lds16(const void* g, void* l) {
    __builtin_amdgcn_global_load_lds(
        (const __attribute__((address_space(1))) void*)g,
        (__attribute__((address_space(3))) void*)l, 16, 0, 0);
}

// ---------------- small prep kernels ----------------

__global__ __launch_bounds__(256) void cvt_x_kernel(const float* __restrict__ x, u16* __restrict__ xh) {
    int i = (blockIdx.x * 256 + threadIdx.x) * 4;
    float4 v = *(const float4*)(x + i);
    u16x4 p;
    p[0] = f2h(v.x); p[1] = f2h(v.y); p[2] = f2h(v.z); p[3] = f2h(v.w);
    *(u16x4*)(xh + i) = p;
}

__global__ __launch_bounds__(256) void concat_bias_kernel(const float* __restrict__ bq, const float* __restrict__ bk,
                                                          const float* __restrict__ bv, float* __restrict__ bqkv) {
    int i = blockIdx.x * 256 + threadIdx.x;
    float v = (i < 768) ? bq[i] : (i < 1536) ? bk[i - 768] : bv[i - 1536];
    bqkv[i] = v;
}

// W stored [k][n] fp32; produce Wt[n][k] f16.  z selects Wq/Wk/Wv/Wo.
__global__ __launch_bounds__(256) void transpose_w_kernel(const float* __restrict__ Wq, const float* __restrict__ Wk,
                                                          const float* __restrict__ Wv, const float* __restrict__ Wo,
                                                          u16* __restrict__ WqkvT, u16* __restrict__ WoT) {
    int z = blockIdx.z;
    const float* W = (z == 0) ? Wq : (z == 1) ? Wk : (z == 2) ? Wv : Wo;
    u16* dst = (z < 3) ? (WqkvT + (size_t)z * 768 * 768) : WoT;
    int k0 = blockIdx.x * 64, n0 = blockIdx.y * 64;
    __shared__ u16 t[64][72];
    int tid = threadIdx.x;
#pragma unroll
    for (int p = 0; p < 16; ++p) {
        int idx = p * 256 + tid;
        int kr = idx >> 6, nc = idx & 63;
        t[kr][nc] = f2h(W[(size_t)(k0 + kr) * 768 + n0 + nc]);
    }
    __syncthreads();
#pragma unroll
    for (int p = 0; p < 16; ++p) {
        int idx = p * 256 + tid;
        int nr = idx >> 6, kc = idx & 63;
        dst[(size_t)(n0 + nr) * 768 + k0 + kc] = t[kc][nr];
    }
}

// Cqkv [4096][2304] f16: V part (cols 1536..2304) -> vT [24][64][2048]
__global__ __launch_bounds__(256) void transpose_v_kernel(const u16* __restrict__ Cqkv, u16* __restrict__ vT) {
    int st = blockIdx.x;    // 32 s-tiles
    int bh = blockIdx.y;    // 24
    int b = bh / NH, h = bh % NH;
    __shared__ u16 t[64][72];
    int tid = threadIdx.x;
#pragma unroll
    for (int p = 0; p < 16; ++p) {
        int idx = p * 256 + tid;
        int sl = idx >> 6, d = idx & 63;
        t[sl][d] = Cqkv[(size_t)(b * SEQ + st * 64 + sl) * DQKV + 1536 + h * DH + d];
    }
    __syncthreads();
#pragma unroll
    for (int p = 0; p < 16; ++p) {
        int idx = p * 256 + tid;
        int dl = idx >> 6, sl = idx & 63;
        vT[(size_t)(bh * 64 + dl) * SEQ + st * 64 + sl] = t[sl][dl];
    }
}

// ---------------- GEMM: C[M][N] = A[M][K] * Bt[N][K]^T + bias ----------------
// 128x128 tile, BK=32, 4 waves each 64x64, global_load_lds(16B) staging,
// double-row XOR swizzle so ds_read_b128 fragments stay ~2-way on banks.

template <bool OUT_F16>
__global__ __launch_bounds__(256) void gemm_bt(const u16* __restrict__ A, const u16* __restrict__ Bt,
                                               const float* __restrict__ bias, void* __restrict__ Cout,
                                               int M, int N, int K) {
    const int tid = threadIdx.x;
    const int wid = tid >> 6;
    const int lane = tid & 63;
    const int qd = lane >> 4;
    const int l15 = lane & 15;

    const int tn = blockIdx.x * 128;
    const int tm = blockIdx.y * 128;
    const int wm = (wid >> 1) * 64;
    const int wn = (wid & 1) * 64;

    __shared__ alignas(16) u16 As[128 * 32];
    __shared__ alignas(16) u16 Bs[128 * 32];

    floatx4 acc[4][4];
#pragma unroll
    for (int i = 0; i < 4; ++i)
#pragma unroll
        for (int j = 0; j < 4; ++j) acc[i][j] = (floatx4)(0.0f);

    // staging decode: slot s (0..511) at LDS byte 16*s; double-row dr=s>>3,
    // stored block bs=s&7, logical bl=bs^(dr&7): row=dr*2+(bl>>2), kblk=bl&3
    const u16* Arow[2];
    const u16* Brow[2];
    u16* lA[2];
    u16* lB[2];
#pragma unroll
    for (int rd = 0; rd < 2; ++rd) {
        int s = rd * 256 + wid * 64 + lane;
        int dr = s >> 3, bs = s & 7, bl = bs ^ (dr & 7);
        int r = dr * 2 + (bl >> 2), c = bl & 3;
        Arow[rd] = A + (size_t)(tm + r) * K + c * 8;
        Brow[rd] = Bt + (size_t)(tn + r) * K + c * 8;
        lA[rd] = As + (size_t)(rd * 256 + wid * 64) * 8;
        lB[rd] = Bs + (size_t)(rd * 256 + wid * 64) * 8;
    }

    for (int kb = 0; kb < K; kb += 32) {
        __syncthreads();
#pragma unroll
        for (int rd = 0; rd < 2; ++rd) {
            gload_lds16(Arow[rd] + kb, lA[rd]);
            gload_lds16(Brow[rd] + kb, lB[rd]);
        }
        __syncthreads();

        halfx8 af[4], bf[4];
#pragma unroll
        for (int i = 0; i < 4; ++i) {
            int r = wm + i * 16 + l15;
            int dr = r >> 1;
            int blk = ((r & 1) * 4 + qd) ^ (dr & 7);
            af[i] = *(const halfx8*)(As + dr * 64 + blk * 8);
            int r2 = wn + i * 16 + l15;
            int dr2 = r2 >> 1;
            int blk2 = ((r2 & 1) * 4 + qd) ^ (dr2 & 7);
            bf[i] = *(const halfx8*)(Bs + dr2 * 64 + blk2 * 8);
        }
#pragma unroll
        for (int i = 0; i < 4; ++i)
#pragma unroll
            for (int j = 0; j < 4; ++j)
                acc[i][j] = __builtin_amdgcn_mfma_f32_16x16x32_f16(af[i], bf[j], acc[i][j], 0, 0, 0);
    }

#pragma unroll
    for (int j = 0; j < 4; ++j) {
        int col = tn + wn + j * 16 + l15;
        float bv = bias[col];
#pragma unroll
        for (int i = 0; i < 4; ++i) {
            int row0 = tm + wm + i * 16 + qd * 4;
#pragma unroll
            for (int r = 0; r < 4; ++r) {
                float v = acc[i][j][r] + bv;
                if (OUT_F16)
                    ((u16*)Cout)[(size_t)(row0 + r) * N + col] = f2h(v);
                else
                    ((float*)Cout)[(size_t)(row0 + r) * N + col] = v;
            }
        }
    }
}

// ---------------- fused attention ----------------
// block = 256 thr (4 waves), grid = (16 q-tiles, 24 bh). Each wave: 32 q rows.
// S^T = K*Q^T (m=key, n=qrow) -> per-lane softmax rows, P -> LDS (b64 packed),
// O^T = V^T * P^T.  All LDS frag reads are contiguous 16B with XOR swizzle.

__global__ __launch_bounds__(256) void attn_kernel(const u16* __restrict__ Cqkv, const u16* __restrict__ vT,
                                                   u16* __restrict__ attn) {
    const int tid = threadIdx.x;
    const int wid = tid >> 6;
    const int lane = tid & 63;
    const int qd = lane >> 4;
    const int l15 = lane & 15;

    const int bh = blockIdx.y;
    const int b = bh / NH, h = bh % NH;
    const int q0 = blockIdx.x * 128;
    const int rowbase = b * SEQ + q0 + wid * 32;

    __shared__ alignas(16) u16 Ks[128 * 64];      // 16 KB  [key][d] swizzled
    __shared__ alignas(16) u16 Vts[64 * 128];     // 16 KB  [d][key] swizzled
    __shared__ alignas(16) u16 Ps[4][32 * 128];   // 32 KB  per-wave P [qrow][key] swizzled

    // Q fragments (reused as B-operand of K*Q^T): Q[qrow=l15+16*i][d=ks*32+qd*8 ..]
    halfx8 aq[2][2];
#pragma unroll
    for (int i = 0; i < 2; ++i)
#pragma unroll
        for (int ks = 0; ks < 2; ++ks)
            aq[i][ks] = *(const halfx8*)(Cqkv + (size_t)(rowbase + i * 16 + l15) * DQKV + h * DH + ks * 32 + qd * 8);

    floatx4 o[4][2];
#pragma unroll
    for (int i = 0; i < 4; ++i)
#pragma unroll
        for (int j = 0; j < 2; ++j) o[i][j] = (floatx4)(0.0f);

    float mstate[2] = {-3.0e38f, -3.0e38f};
    float lstate[2] = {0.0f, 0.0f};
    const float cscale = 0.125f * 1.44269504088896340736f;  // 1/sqrt(64) * log2(e)

    u16* ps = &Ps[wid][0];

    for (int kt = 0; kt < 16; ++kt) {
        __syncthreads();
#pragma unroll
        for (int c4 = 0; c4 < 4; ++c4) {
            int s = c4 * 256 + wid * 64 + lane;
            {   // K tile: 128 rows x 8 blocks, swizzle bl = bs ^ (r&7)
                int r = s >> 3, bs = s & 7, bl = bs ^ (r & 7);
                const u16* g = Cqkv + (size_t)(b * SEQ + kt * 128 + r) * DQKV + 768 + h * DH + bl * 8;
                gload_lds16(g, Ks + (size_t)(c4 * 256 + wid * 64) * 8);
            }
            {   // V^T tile: 64 rows x 16 blocks, swizzle bl = bs ^ (r&15)
                int r = s >> 4, bs = s & 15, bl = bs ^ (r & 15);
                const u16* g = vT + (size_t)(bh * 64 + r) * SEQ + kt * 128 + bl * 8;
                gload_lds16(g, Vts + (size_t)(c4 * 256 + wid * 64) * 8);
            }
        }
        __syncthreads();

        // S^T = K * Q^T : sc[mi][j2], key = mi*16 + qd*4 + reg, qrow = j2*16 + l15
        floatx4 sc[8][2];
#pragma unroll
        for (int mi = 0; mi < 8; ++mi)
#pragma unroll
            for (int j2 = 0; j2 < 2; ++j2) sc[mi][j2] = (floatx4)(0.0f);
#pragma unroll
        for (int ks = 0; ks < 2; ++ks)
#pragma unroll
            for (int mi = 0; mi < 8; ++mi) {
                int r = mi * 16 + l15;
                halfx8 ak = *(const halfx8*)(Ks + r * 64 + (((ks * 4 + qd) ^ (r & 7)) * 8));
#pragma unroll
                for (int j2 = 0; j2 < 2; ++j2)
                    sc[mi][j2] = __builtin_amdgcn_mfma_f32_16x16x32_f16(ak, aq[j2][ks], sc[mi][j2], 0, 0, 0);
            }

        // online softmax, per lane 2 q-rows
        float mnew[2], alpha[2], rsum[2];
#pragma unroll
        for (int j2 = 0; j2 < 2; ++j2) {
            float rm = sc[0][j2][0];
#pragma unroll
            for (int mi = 0; mi < 8; ++mi)
#pragma unroll
                for (int r = 0; r < 4; ++r) rm = fmaxf(rm, sc[mi][j2][r]);
            rm = fmaxf(rm, __shfl_xor(rm, 16, 64));
            rm = fmaxf(rm, __shfl_xor(rm, 32, 64));
            mnew[j2] = fmaxf(mstate[j2], rm * cscale);
            alpha[j2] = __builtin_amdgcn_exp2f(mstate[j2] - mnew[j2]);
            mstate[j2] = mnew[j2];
            rsum[j2] = 0.0f;
        }
#pragma unroll
        for (int mi = 0; mi < 8; ++mi)
#pragma unroll
            for (int j2 = 0; j2 < 2; ++j2) {
                u16x4 pk;
#pragma unroll
                for (int r = 0; r < 4; ++r) {
                    float p = __builtin_amdgcn_exp2f(sc[mi][j2][r] * cscale - mnew[j2]);
                    rsum[j2] += p;
                    pk[r] = f2h(p);
                }
                int key0 = mi * 16 + qd * 4;
                int addr = (j2 * 16 + l15) * 128 + (((key0 >> 3) ^ l15) * 8) + (key0 & 7);
                *(u16x4*)(ps + addr) = pk;  // ds_write_b64
            }
#pragma unroll
        for (int j2 = 0; j2 < 2; ++j2) {
            float s2 = rsum[j2];
            s2 += __shfl_xor(s2, 16, 64);
            s2 += __shfl_xor(s2, 32, 64);
            lstate[j2] = lstate[j2] * alpha[j2] + s2;
        }
        // rescale O^T (col = qrow = j2*16 + l15 -> alpha is per-lane scalar)
#pragma unroll
        for (int ip = 0; ip < 4; ++ip)
#pragma unroll
            for (int j2 = 0; j2 < 2; ++j2)
#pragma unroll
                for (int r = 0; r < 4; ++r) o[ip][j2][r] *= alpha[j2];

        // O^T += V^T * P^T
#pragma unroll
        for (int ks2 = 0; ks2 < 4; ++ks2) {
            halfx8 bp[2];
#pragma unroll
            for (int j2 = 0; j2 < 2; ++j2)
                bp[j2] = *(const halfx8*)(ps + (j2 * 16 + l15) * 128 + (((ks2 * 4 + qd) ^ l15) * 8));
#pragma unroll
            for (int ip = 0; ip < 4; ++ip) {
                int r = ip * 16 + l15;
                halfx8 av = *(const halfx8*)(Vts + r * 128 + (((ks2 * 4 + qd) ^ (r & 15)) * 8));
#pragma unroll
                for (int j2 = 0; j2 < 2; ++j2)
                    o[ip][j2] = __builtin_amdgcn_mfma_f32_16x16x32_f16(av, bp[j2], o[ip][j2], 0, 0, 0);
            }
        }
    }

    // epilogue: attn[token][h*64+d] f16, pack 4 consecutive d per 8B store
#pragma unroll
    for (int j2 = 0; j2 < 2; ++j2) {
        float inv = __builtin_amdgcn_rcpf(lstate[j2]);
        int token = rowbase + j2 * 16 + l15;
#pragma unroll
        for (int ip = 0; ip < 4; ++ip) {
            u16x4 pk;
#pragma unroll
            for (int r = 0; r < 4; ++r) pk[r] = f2h(o[ip][j2][r] * inv);
            *(u16x4*)(attn + (size_t)token * D_MODEL + h * DH + ip * 16 + qd * 4) = pk;
        }
    }
}

// ---------------- launch ----------------

extern "C" void kernel_launch(void* const* d_in, const int* in_sizes, int n_in,
                              void* d_out, int out_size, void* d_ws, size_t ws_size,
                              hipStream_t stream) {
    const float* x  = (const float*)d_in[0];
    const float* Wq = (const float*)d_in[1];
    const float* bq = (const float*)d_in[2];
    const float* Wk = (const float*)d_in[3];
    const float* bk = (const float*)d_in[4];
    const float* Wv = (const float*)d_in[5];
    const float* bv = (const float*)d_in[6];
    const float* Wo = (const float*)d_in[7];
    const float* bo = (const float*)d_in[8];

    char* ws = (char*)d_ws;
    size_t off = 0;
    auto take = [&](size_t bytes) -> char* {
        char* p = ws + off;
        off += (bytes + 255) & ~(size_t)255;
        return p;
    };
    u16*   xh    = (u16*)take((size_t)MTOK * D_MODEL * 2);
    u16*   WqkvT = (u16*)take((size_t)DQKV * D_MODEL * 2);
    u16*   WoT   = (u16*)take((size_t)D_MODEL * D_MODEL * 2);
    float* bqkv  = (float*)take((size_t)DQKV * 4);
    u16*   Cqkv  = (u16*)take((size_t)MTOK * DQKV * 2);
    u16*   vTb   = (u16*)take((size_t)BATCH * NH * DH * SEQ * 2);
    u16*   attn  = (u16*)take((size_t)MTOK * D_MODEL * 2);

    cvt_x_kernel<<<MTOK * D_MODEL / 1024, 256, 0, stream>>>(x, xh);
    concat_bias_kernel<<<DQKV / 256, 256, 0, stream>>>(bq, bk, bv, bqkv);
    transpose_w_kernel<<<dim3(12, 12, 4), 256, 0, stream>>>(Wq, Wk, Wv, Wo, WqkvT, WoT);
    gemm_bt<true><<<dim3(DQKV / 128, MTOK / 128), 256, 0, stream>>>(xh, WqkvT, bqkv, Cqkv, MTOK, DQKV, D_MODEL);
    transpose_v_kernel<<<dim3(SEQ / 64, BATCH * NH), 256, 0, stream>>>(Cqkv, vTb);
    attn_kernel<<<dim3(SEQ / 128, BATCH * NH), 256, 0, stream>>>(Cqkv, vTb, attn);
    gemm_bt<false><<<dim3(D_MODEL / 128, MTOK / 128), 256, 0, stream>>>(attn, WoT, bo, d_out, MTOK, D_MODEL, D_MODEL);
}